// Round 1
// baseline (120.322 us; speedup 1.0000x reference)
//
#include <hip/hip_runtime.h>
#include <stdint.h>

typedef short short8 __attribute__((ext_vector_type(8)));
typedef float f32x4 __attribute__((ext_vector_type(4)));

#define B_TOTAL 8192
#define DDIM 256
#define BM 128
#define BN 64
#define NSPLIT 8
#define COLS_PER (B_TOTAL / NSPLIT)   // 1024
#define ITERS (COLS_PER / BN)         // 16
#define EXP2_SCALE 14.426950408889634f  // (1/T)/ln2 = 10/ln2

typedef __attribute__((address_space(3))) char lds_char;
typedef __attribute__((address_space(1))) const char gbl_char;

__device__ __forceinline__ unsigned short f2bf(float f) {
  unsigned int u = __builtin_bit_cast(unsigned int, f);
  u = (u + 0x7FFFu + ((u >> 16) & 1u)) >> 16;   // RNE; inputs are finite
  return (unsigned short)u;
}

// ---------------- prep: fp32->bf16 convert, label pack, zero accumulators ----
__global__ __launch_bounds__(256) void prep_all(
    const float* __restrict__ E, const int* __restrict__ lab,
    unsigned short* __restrict__ Eb, unsigned int* __restrict__ plab,
    float* __restrict__ posAll) {
  const int t = blockIdx.x * 256 + threadIdx.x;   // 0..262143, 8 floats each
  const float4* s4 = (const float4*)E + (size_t)t * 2;
  float4 v0 = s4[0], v1 = s4[1];
  short8 o;
  o[0] = (short)f2bf(v0.x); o[1] = (short)f2bf(v0.y);
  o[2] = (short)f2bf(v0.z); o[3] = (short)f2bf(v0.w);
  o[4] = (short)f2bf(v1.x); o[5] = (short)f2bf(v1.y);
  o[6] = (short)f2bf(v1.z); o[7] = (short)f2bf(v1.w);
  *(short8*)(Eb + (size_t)t * 8) = o;
  if (t < B_TOTAL) {
    int4 l = ((const int4*)lab)[t];   // labels as int32 per harness conversion
    plab[t] = (unsigned int)(l.x & 0xFF) | ((unsigned int)(l.y & 0xFF) << 8)
            | ((unsigned int)(l.z & 0xFF) << 16) | ((unsigned int)(l.w & 0xFF) << 24);
  }
  if (t < 2 * B_TOTAL) posAll[t] = 0.0f;   // posArr+allArr contiguous
}

// ---------------- fused sim/exp/mask/rowsum kernel ---------------------------
struct __align__(16) SMem {
  char btile[BN * DDIM * 2];   // 32 KB, XOR-swizzled 16B chunks
  unsigned int plds[BN];
};

template <int DIAG>
__device__ __forceinline__ void do_epilogue(
    const f32x4 (&acc)[4][2], int colbase, int l15,
    const unsigned int (&pi)[2][4], const int (&irow)[2][4],
    const unsigned int* plds, float (&pos_s)[2][4], float (&all_s)[2][4]) {
#pragma unroll
  for (int n = 0; n < 4; ++n) {
    const int j = colbase + n * 16 + l15;
    const unsigned int pj = plds[n * 16 + l15];
#pragma unroll
    for (int m = 0; m < 2; ++m) {
#pragma unroll
      for (int q = 0; q < 4; ++q) {
        float e = exp2f(acc[n][m][q] * EXP2_SCALE);   // = exp(sim/T)
        if (DIAG) { if (j == irow[m][q]) e = 0.0f; }  // drop diagonal from both sums
        unsigned int x = pi[m][q] ^ pj;
        unsigned int tz = (x - 0x01010101u) & ~x & 0x80808080u;  // any byte equal
        all_s[m][q] += e;
        pos_s[m][q] += tz ? e : 0.0f;
      }
    }
  }
}

__global__ __launch_bounds__(256, 2) void main_kernel(
    const unsigned short* __restrict__ Eb, const unsigned int* __restrict__ plab,
    float* __restrict__ posArr, float* __restrict__ allArr) {
  __shared__ SMem sm;
  const int tid = threadIdx.x;
  const int lane = tid & 63;
  const int wid = tid >> 6;        // 4 waves, each owns 32 rows
  const int l15 = lane & 15;
  const int l4 = lane >> 4;
  const int rb = (int)blockIdx.x & 63;
  const int cs = (int)blockIdx.x >> 6;
  const int rowbase = rb * BM;
  const int colstart = cs * COLS_PER;

  // A fragments: register-resident, 32 rows x 256 k per wave
  short8 afrag[2][8];
#pragma unroll
  for (int m = 0; m < 2; ++m) {
    const int row = rowbase + wid * 32 + m * 16 + l15;
    const unsigned short* rp = Eb + (size_t)row * DDIM + l4 * 8;
#pragma unroll
    for (int k = 0; k < 8; ++k) afrag[m][k] = *(const short8*)(rp + k * 32);
  }

  // per-lane row ids + packed labels for the 8 rows this lane accumulates
  unsigned int pi[2][4];
  int irow[2][4];
#pragma unroll
  for (int m = 0; m < 2; ++m)
#pragma unroll
    for (int q = 0; q < 4; ++q) {
      const int i = rowbase + wid * 32 + m * 16 + l4 * 4 + q;
      irow[m][q] = i;
      pi[m][q] = plab[i];
    }

  float pos_s[2][4] = {};
  float all_s[2][4] = {};

  for (int it = 0; it < ITERS; ++it) {
    const int colbase = colstart + it * BN;
    __syncthreads();   // previous iter's LDS reads done
    // stage B tile: linear LDS dest, inverse-swizzled global source (rule #21)
#pragma unroll
    for (int q = 0; q < 8; ++q) {
      const unsigned int L = (unsigned int)wid * 8192u + (unsigned int)q * 1024u +
                             (unsigned int)lane * 16u;
      const unsigned int r = L >> 9;          // B-tile row (0..63)
      const unsigned int s = (L >> 4) & 31u;  // stored 16B chunk in row
      const unsigned int c = s ^ (r & 7u);    // logical chunk (involution)
      const char* src = (const char*)(Eb + (size_t)(colbase + (int)r) * DDIM + c * 8);
      char* dst = sm.btile + (unsigned int)wid * 8192u + (unsigned int)q * 1024u;
      __builtin_amdgcn_global_load_lds((gbl_char*)src, (lds_char*)dst, 16, 0, 0);
    }
    if (tid < BN) sm.plds[tid] = plab[colbase + tid];
    __syncthreads();   // staging visible (syncthreads drains vmcnt)

    f32x4 acc[4][2];
#pragma unroll
    for (int n = 0; n < 4; ++n)
#pragma unroll
      for (int m = 0; m < 2; ++m) acc[n][m] = (f32x4){0.f, 0.f, 0.f, 0.f};

#pragma unroll
    for (int k = 0; k < 8; ++k) {
      short8 b[4];
#pragma unroll
      for (int n = 0; n < 4; ++n) {
        const unsigned int rr = (unsigned int)(n * 16 + l15);
        const unsigned int cdx = (unsigned int)(k * 4 + l4);
        const unsigned int s = cdx ^ (rr & 7u);   // swizzled read
        b[n] = *(const short8*)(sm.btile + rr * 512u + s * 16u);
      }
#pragma unroll
      for (int n = 0; n < 4; ++n)
#pragma unroll
        for (int m = 0; m < 2; ++m)
          acc[n][m] = __builtin_amdgcn_mfma_f32_16x16x32_bf16(
              afrag[m][k], b[n], acc[n][m], 0, 0, 0);
    }

    const bool hasDiag = (colbase < rowbase + BM) && (rowbase < colbase + BN);
    if (hasDiag)
      do_epilogue<1>(acc, colbase, l15, pi, irow, sm.plds, pos_s, all_s);
    else
      do_epilogue<0>(acc, colbase, l15, pi, irow, sm.plds, pos_s, all_s);
  }

  // reduce across the 16 lanes sharing the same rows, then one atomic per row
#pragma unroll
  for (int m = 0; m < 2; ++m)
#pragma unroll
    for (int q = 0; q < 4; ++q) {
      float p = pos_s[m][q], al = all_s[m][q];
      p += __shfl_xor(p, 1); p += __shfl_xor(p, 2);
      p += __shfl_xor(p, 4); p += __shfl_xor(p, 8);
      al += __shfl_xor(al, 1); al += __shfl_xor(al, 2);
      al += __shfl_xor(al, 4); al += __shfl_xor(al, 8);
      if (l15 == 0) {
        atomicAdd(&posArr[irow[m][q]], p);
        atomicAdd(&allArr[irow[m][q]], al);
      }
    }
}

// ---------------- finalize: row losses + mean --------------------------------
__global__ __launch_bounds__(1024) void finalize_kernel(
    const float* __restrict__ posArr, const float* __restrict__ allArr,
    float* __restrict__ out) {
  float ls = 0.f, cnt = 0.f;
#pragma unroll
  for (int k = 0; k < 8; ++k) {
    const int i = threadIdx.x + k * 1024;
    const float p = posArr[i];
    const float al = allArr[i];
    if (p > 0.f) { ls += -logf(p / (al + 1e-8f)); cnt += 1.f; }
  }
  for (int m = 1; m < 64; m <<= 1) { ls += __shfl_xor(ls, m); cnt += __shfl_xor(cnt, m); }
  __shared__ float sls[16], scnt[16];
  const int w = threadIdx.x >> 6;
  if ((threadIdx.x & 63) == 0) { sls[w] = ls; scnt[w] = cnt; }
  __syncthreads();
  if (threadIdx.x == 0) {
    float L = 0.f, C = 0.f;
    for (int i = 0; i < 16; ++i) { L += sls[i]; C += scnt[i]; }
    out[0] = (C > 0.f) ? L / fmaxf(C, 1.f) : 0.f;
  }
}

// ---------------- launch -----------------------------------------------------
extern "C" void kernel_launch(void* const* d_in, const int* in_sizes, int n_in,
                              void* d_out, int out_size, void* d_ws, size_t ws_size,
                              hipStream_t stream) {
  const float* E = (const float*)d_in[0];
  const int* lab = (const int*)d_in[1];
  float* out = (float*)d_out;
  char* ws = (char*)d_ws;

  unsigned short* Eb = (unsigned short*)ws;                       // 4 MB
  unsigned int* plab = (unsigned int*)(ws + 4u * 1024u * 1024u);  // 32 KB
  float* posArr = (float*)(ws + 4u * 1024u * 1024u + 32u * 1024u);
  float* allArr = posArr + B_TOTAL;

  prep_all<<<1024, 256, 0, stream>>>(E, lab, Eb, plab, posArr);
  main_kernel<<<(B_TOTAL / BM) * NSPLIT, 256, 0, stream>>>(Eb, plab, posArr, allArr);
  finalize_kernel<<<1, 1024, 0, stream>>>(posArr, allArr, out);
}